// Round 3
// baseline (100.889 us; speedup 1.0000x reference)
//
#include <hip/hip_runtime.h>
#include <math.h>

#define B   8
#define TQ  48
#define TK  128
#define F   64
#define ET  64
#define H   8
#define DK  8
#define D   128   // 2*F

// ---------------------------------------------------------------------------
// Kernel A: time-embed + linear projection for keys (T, Wk) and queries
// (alpha, Wq). Rows 0..B*TK-1 are keys, B*TK.. are queries.
// One wave per row; 4 rows per block; 352 blocks.
// Key output layout [B,H,TK,DK] so kernel B reads contiguous DK=8 chunks.
// ---------------------------------------------------------------------------
__global__ __launch_bounds__(256) void embed_proj_kernel(
    const float* __restrict__ T,      // [B,TK]
    const float* __restrict__ alpha,  // [B,TQ]
    const float* __restrict__ w_lin, const float* __restrict__ b_lin,
    const float* __restrict__ w_per, const float* __restrict__ b_per,
    const float* __restrict__ Wq, const float* __restrict__ bq,
    const float* __restrict__ Wk, const float* __restrict__ bk,
    float* __restrict__ kws,          // [B,H,TK,DK]
    float* __restrict__ qws)          // [B,TQ,ET]
{
    __shared__ float es[4][ET];
    const int tid = threadIdx.x;
    const int rl  = tid >> 6;
    const int o   = tid & 63;
    const int row = blockIdx.x * 4 + rl;   // 0..1407

    const bool is_key = row < B * TK;
    const float t = is_key ? T[row] : alpha[row - B * TK];

    float e;
    if (o == 0) e = t * w_lin[0] + b_lin[0];
    else        e = sinf(t * w_per[o - 1] + b_per[o - 1]);
    es[rl][o] = e;
    __syncthreads();

    const float* Wp   = is_key ? Wk : Wq;
    const float* bias = is_key ? bk : bq;
    float acc = bias[o];
    #pragma unroll 8
    for (int i = 0; i < ET; ++i)
        acc = fmaf(es[rl][i], Wp[i * ET + o], acc);

    if (is_key) {
        const int b  = row >> 7;
        const int kk = row & 127;
        const int h  = o >> 3;
        const int dk = o & 7;
        kws[((b * H + h) * TK + kk) * DK + dk] = acc;
    } else {
        const int r = row - B * TK;
        qws[r * ET + o] = acc;
    }
}

// ---------------------------------------------------------------------------
// Kernel B: one block per (b,q), 512 threads (8 waves -> ~3 waves/SIMD
// chip-wide; the old 256-thread version left the chip at 1.5 waves/SIMD).
//   1. stage X[b] (32KB) + packed mask bits (1KB), load q row
//   2. scores s[h][k] = q[h]·k[h][k]/sqrt(DK)          (float4 k reads)
//   3. per-h max (shfl reduce) -> E[h][k] = exp(s-max)
//   4. masked accumulate, k-split x4, f-vectorized x4:
//        den_f = sum_k E*m_kf ; num_f = sum_k E*m_kf*X_kf
//      (exp(-10000-max)==0.0f exactly in f32 -> masked terms are exactly 0,
//       bit-identical to the reference's masked_fill path)
//      channels f+64: out = sum_k p*m = den/den = 1  (0 if all-masked)
//   5. fused out-projection x[1024] @ Wo[1024,64], 32-way split-K, float4
// ---------------------------------------------------------------------------
__global__ __launch_bounds__(512) void attn_kernel(
    const float* __restrict__ X,     // [B,TK,F]
    const float* __restrict__ mask,  // [B,TK,F]
    const float* __restrict__ kws,   // [B,H,TK,DK]
    const float* __restrict__ qws,   // [B,TQ,ET]
    const float* __restrict__ Wo,    // [H*D, ET]
    const float* __restrict__ bo,    // [ET]
    float* __restrict__ out)         // [B,TQ,ET]
{
    __shared__ float qs[ET];
    __shared__ float Es[H][TK];                 // 4 KB
    __shared__ float maxs[H];
    __shared__ float Xs[TK][F];                 // 32 KB
    __shared__ unsigned long long Mb[TK];       // 1 KB
    __shared__ float xs[H * D];                 // 4 KB
    __shared__ float pden[4][H * F];            // 8 KB
    __shared__ float pnum[4][H * F];            // 8 KB
    __shared__ float red[32][ET];               // 8 KB   (~65 KB total)

    const int tid = threadIdx.x;                // 0..511
    const int b = blockIdx.x / TQ;
    const int q = blockIdx.x % TQ;

    // ---- stage ----
    if (tid < ET) qs[tid] = qws[(b * TQ + q) * ET + tid];

    const float4* X4  = (const float4*)(X + b * TK * F);
    float4*       Xs4 = (float4*)&Xs[0][0];
    #pragma unroll
    for (int i = 0; i < 4; ++i)                 // 2048 float4 / 512 threads
        Xs4[tid + 512 * i] = X4[tid + 512 * i];

    {   // pack mask bits: wave w handles rows [w*16, w*16+16)
        const int wave = tid >> 6, lane = tid & 63;
        const float* mrow = mask + b * TK * F;
        #pragma unroll 4
        for (int i = 0; i < 16; ++i) {
            const int kk = wave * 16 + i;
            const unsigned long long bal = __ballot(mrow[kk * F + lane] != 0.0f);
            if (lane == 0) Mb[kk] = bal;
        }
    }
    __syncthreads();

    // ---- scores: 1024 (h,k) items / 512 threads ----
    const float4* k4 = (const float4*)(kws + b * H * TK * DK);
    #pragma unroll
    for (int i = 0; i < 2; ++i) {
        const int p = tid + 512 * i;
        const int h = p >> 7, kk = p & 127;
        const float4 a0 = k4[(h * TK + kk) * 2 + 0];
        const float4 a1 = k4[(h * TK + kk) * 2 + 1];
        const float* qh = &qs[h * DK];
        float s = a0.x * qh[0] + a0.y * qh[1] + a0.z * qh[2] + a0.w * qh[3]
                + a1.x * qh[4] + a1.y * qh[5] + a1.z * qh[6] + a1.w * qh[7];
        Es[h][kk] = s * 0.35355339059327373f;   // 1/sqrt(8)
    }
    __syncthreads();

    // ---- per-h max (32 threads per h; shfl stays inside wave halves) ----
    if (tid < 256) {
        const int h = tid >> 5, j = tid & 31;
        float m = fmaxf(fmaxf(Es[h][j], Es[h][j + 32]),
                        fmaxf(Es[h][j + 64], Es[h][j + 96]));
        #pragma unroll
        for (int dlt = 16; dlt >= 1; dlt >>= 1)
            m = fmaxf(m, __shfl_xor(m, dlt));
        if (j == 0) maxs[h] = m;
    }
    __syncthreads();

    // ---- E = exp(s - max) ----
    #pragma unroll
    for (int i = 0; i < 2; ++i) {
        const int p = tid + 512 * i;
        const int h = p >> 7, kk = p & 127;
        Es[h][kk] = expf(Es[h][kk] - maxs[h]);
    }
    __syncthreads();

    // ---- masked accumulate: thread = (ksec, h, f4); 32 iters, float4 Xs ----
    {
        const int f4 = (tid & 15) * 4;          // f base
        const int h  = (tid >> 4) & 7;
        const int ks = tid >> 7;                // k section, uniform per wave
        const int k0 = ks * 32;
        float d0 = 0, d1 = 0, d2 = 0, d3 = 0;
        float n0 = 0, n1 = 0, n2 = 0, n3 = 0;
        #pragma unroll 8
        for (int i = 0; i < 32; ++i) {
            const int kk = k0 + i;
            const float e  = Es[h][kk];                       // broadcast
            const float4 x = *(const float4*)&Xs[kk][f4];     // 2-way: free
            const unsigned int mb = (unsigned int)(Mb[kk] >> f4);
            const float e0 = (mb & 1u) ? e : 0.0f;
            const float e1 = (mb & 2u) ? e : 0.0f;
            const float e2 = (mb & 4u) ? e : 0.0f;
            const float e3 = (mb & 8u) ? e : 0.0f;
            d0 += e0; d1 += e1; d2 += e2; d3 += e3;
            n0 = fmaf(e0, x.x, n0); n1 = fmaf(e1, x.y, n1);
            n2 = fmaf(e2, x.z, n2); n3 = fmaf(e3, x.w, n3);
        }
        const int base = h * F + f4;
        *(float4*)&pden[ks][base] = make_float4(d0, d1, d2, d3);
        *(float4*)&pnum[ks][base] = make_float4(n0, n1, n2, n3);
    }
    __syncthreads();

    // ---- combine 4 k-sections: 512 threads <-> 512 (h,f) pairs ----
    {
        const int h = tid >> 6, f = tid & 63;
        const int idx = h * F + f;
        const float den = pden[0][idx] + pden[1][idx] + pden[2][idx] + pden[3][idx];
        const float num = pnum[0][idx] + pnum[1][idx] + pnum[2][idx] + pnum[3][idx];
        float outX, outM;
        if (den > 0.0f) {
            outX = num / den;
            outM = 1.0f;                        // sum_k p*mask == den/den
        } else {
            // all-masked column: reference softmax is uniform 1/TK
            float sX = 0.0f;
            for (int kk = 0; kk < TK; ++kk) sX += Xs[kk][f];
            outX = sX * (1.0f / TK);
            outM = 0.0f;
        }
        xs[h * D + f]      = outX;
        xs[h * D + 64 + f] = outM;
    }
    __syncthreads();

    // ---- out-projection: 32 parts x 16 e4-groups, float4 Wo loads ----
    {
        const int e4 = (tid & 15) * 4;
        const int p  = tid >> 4;                // 0..31
        const int j0 = p * 32;
        float ax = 0, ay = 0, az = 0, aw = 0;
        #pragma unroll 8
        for (int i = 0; i < 32; ++i) {
            const int j = j0 + i;
            const float xj = xs[j];                           // broadcast
            const float4 w = *(const float4*)&Wo[j * ET + e4];
            ax = fmaf(xj, w.x, ax); ay = fmaf(xj, w.y, ay);
            az = fmaf(xj, w.z, az); aw = fmaf(xj, w.w, aw);
        }
        *(float4*)&red[p][e4] = make_float4(ax, ay, az, aw);
    }
    __syncthreads();
    if (tid < ET) {
        float acc = bo[tid];
        #pragma unroll
        for (int p = 0; p < 32; ++p) acc += red[p][tid];      // 2-way: free
        out[(b * TQ + q) * ET + tid] = acc;
    }
}

extern "C" void kernel_launch(void* const* d_in, const int* in_sizes, int n_in,
                              void* d_out, int out_size, void* d_ws, size_t ws_size,
                              hipStream_t stream) {
    const float* X      = (const float*)d_in[0];
    const float* mask_X = (const float*)d_in[1];
    const float* T      = (const float*)d_in[2];
    const float* alpha  = (const float*)d_in[3];
    const float* w_lin  = (const float*)d_in[4];
    const float* b_lin  = (const float*)d_in[5];
    const float* w_per  = (const float*)d_in[6];
    const float* b_per  = (const float*)d_in[7];
    const float* Wq     = (const float*)d_in[8];
    const float* bq     = (const float*)d_in[9];
    const float* Wk     = (const float*)d_in[10];
    const float* bk     = (const float*)d_in[11];
    const float* Wo     = (const float*)d_in[12];
    const float* bo     = (const float*)d_in[13];
    float* out = (float*)d_out;

    float* kws = (float*)d_ws;                    // B*H*TK*DK = 65536 floats
    float* qws = kws + B * H * TK * DK;           // B*TQ*ET   = 24576 floats

    embed_proj_kernel<<<dim3((B * TK + B * TQ) / 4), dim3(256), 0, stream>>>(
        T, alpha, w_lin, b_lin, w_per, b_per, Wq, bq, Wk, bk, kws, qws);

    attn_kernel<<<dim3(B * TQ), dim3(512), 0, stream>>>(
        X, mask_X, kws, qws, Wo, bo, out);
}

// Round 6
// 99.125 us; speedup vs baseline: 1.0178x; 1.0178x over previous
//
#include <hip/hip_runtime.h>
#include <math.h>

#define B   8
#define TQ  48
#define TK  128
#define F   64
#define ET  64
#define H   8
#define DK  8
#define D   128   // 2*F

// ---------------------------------------------------------------------------
// Kernel A: time-embed + linear projection for keys (T, Wk) and queries
// (alpha, Wq). One wave per row; 4 rows per block; 352 blocks.
// Key output layout [B,H,TK,DK] so kernel B reads contiguous DK=8 chunks.
// ---------------------------------------------------------------------------
__global__ __launch_bounds__(256) void embed_proj_kernel(
    const float* __restrict__ T,      // [B,TK]
    const float* __restrict__ alpha,  // [B,TQ]
    const float* __restrict__ w_lin, const float* __restrict__ b_lin,
    const float* __restrict__ w_per, const float* __restrict__ b_per,
    const float* __restrict__ Wq, const float* __restrict__ bq,
    const float* __restrict__ Wk, const float* __restrict__ bk,
    float* __restrict__ kws,          // [B,H,TK,DK]
    float* __restrict__ qws)          // [B,TQ,ET]
{
    __shared__ float es[4][ET];
    const int tid = threadIdx.x;
    const int rl  = tid >> 6;
    const int o   = tid & 63;
    const int row = blockIdx.x * 4 + rl;   // 0..1407

    const bool is_key = row < B * TK;
    const float t = is_key ? T[row] : alpha[row - B * TK];

    float e;
    if (o == 0) e = t * w_lin[0] + b_lin[0];
    else        e = sinf(t * w_per[o - 1] + b_per[o - 1]);
    es[rl][o] = e;
    __syncthreads();

    const float* Wp   = is_key ? Wk : Wq;
    const float* bias = is_key ? bk : bq;
    float acc = bias[o];
    #pragma unroll 8
    for (int i = 0; i < ET; ++i)
        acc = fmaf(es[rl][i], Wp[i * ET + o], acc);

    if (is_key) {
        const int b  = row >> 7;
        const int kk = row & 127;
        const int h  = o >> 3;
        const int dk = o & 7;
        kws[((b * H + h) * TK + kk) * DK + dk] = acc;
    } else {
        const int r = row - B * TK;
        qws[r * ET + o] = acc;
    }
}

// ---------------------------------------------------------------------------
// Kernel B v2: one block per (b,q), 512 threads, 4 barriers.
//  P1 (barrier-free, per-wave): wave w owns head h=w:
//      - mask ballots for rows w*16..w*16+15  -> Mb
//      - scores s[h][k] for k=lane, lane+64 (float4 kws reads)
//      - full-wave64 shfl max, exp, write Est[k][h] (transposed)
//  P2: thread=(ksec=wave, f): 16 k's, X[k][f] read ONCE from L2 (coalesced),
//      update all 8 heads in registers (Est row = 2 b128 broadcasts);
//      partials -> pdn[ksec][h][f] (float2 den,num)
//      (exp(-10000-max)==0.0f exactly in f32 -> masked terms exactly 0,
//       matching the reference's masked_fill path)
//  P3: thread=(h=wave, f=lane): combine 8 sections, outX=num/den,
//      channel f+64: sum_k p*mask = den/den = 1 (0 if all-masked)
//  P4: projection x[1024] @ Wo[1024,64]: 32 parts x 16 e4-groups, float4
//  P5: final 32-way reduce + bias + store
// ---------------------------------------------------------------------------
__global__ __launch_bounds__(512) void attn_kernel(
    const float* __restrict__ X,     // [B,TK,F]
    const float* __restrict__ mask,  // [B,TK,F]
    const float* __restrict__ kws,   // [B,H,TK,DK]
    const float* __restrict__ qws,   // [B,TQ,ET]
    const float* __restrict__ Wo,    // [H*D, ET]
    const float* __restrict__ bo,    // [ET]
    float* __restrict__ out)         // [B,TQ,ET]
{
    __shared__ float Est[TK][H];                 // 4 KB, E transposed
    __shared__ unsigned long long Mb[TK];        // 1 KB
    __shared__ float2 pdn[8][H][F];              // 32 KB (den,num) partials
    __shared__ float xs[H * D];                  // 4 KB
    __shared__ float red[32][ET];                // 8 KB   (~49 KB total)

    const int tid  = threadIdx.x;                // 0..511
    const int wave = tid >> 6, lane = tid & 63;
    const int b = blockIdx.x / TQ;
    const int q = blockIdx.x % TQ;

    // ---- P1: per-wave, no inter-wave dependencies ----
    {
        const float* mrow = mask + b * TK * F;
        #pragma unroll 4
        for (int i = 0; i < 16; ++i) {
            const int kk = wave * 16 + i;
            const unsigned long long bal = __ballot(mrow[kk * F + lane] != 0.0f);
            if (lane == 0) Mb[kk] = bal;
        }

        const float* qrow = qws + (b * TQ + q) * ET + wave * DK;
        float qh[8];
        #pragma unroll
        for (int d = 0; d < 8; ++d) qh[d] = qrow[d];   // wave-uniform

        const float4* k4 = (const float4*)(kws + (b * H + wave) * TK * DK);
        const float4 a0 = k4[lane * 2 + 0];
        const float4 a1 = k4[lane * 2 + 1];
        const float4 c0 = k4[(lane + 64) * 2 + 0];
        const float4 c1 = k4[(lane + 64) * 2 + 1];
        const float inv = 0.35355339059327373f;        // 1/sqrt(8)
        float s0 = (a0.x*qh[0] + a0.y*qh[1] + a0.z*qh[2] + a0.w*qh[3]
                  + a1.x*qh[4] + a1.y*qh[5] + a1.z*qh[6] + a1.w*qh[7]) * inv;
        float s1 = (c0.x*qh[0] + c0.y*qh[1] + c0.z*qh[2] + c0.w*qh[3]
                  + c1.x*qh[4] + c1.y*qh[5] + c1.z*qh[6] + c1.w*qh[7]) * inv;

        float m = fmaxf(s0, s1);
        #pragma unroll
        for (int dlt = 32; dlt >= 1; dlt >>= 1)
            m = fmaxf(m, __shfl_xor(m, dlt));          // all-64-lane max

        Est[lane][wave]      = expf(s0 - m);
        Est[lane + 64][wave] = expf(s1 - m);
    }
    __syncthreads();

    // ---- P2: k-section accumulate; X read once per (k,f) per block ----
    {
        const int f = lane;
        const float* Xrow = X + b * TK * F + f;
        float den[8], num[8];
        #pragma unroll
        for (int h = 0; h < 8; ++h) { den[h] = 0.0f; num[h] = 0.0f; }
        const int k0 = wave * 16;
        #pragma unroll 4
        for (int i = 0; i < 16; ++i) {
            const int kk = k0 + i;
            const float x = Xrow[kk * F];                       // coalesced L2
            const unsigned int bit = (unsigned int)(Mb[kk] >> f) & 1u;
            const float4 e0 = *(const float4*)&Est[kk][0];      // broadcast
            const float4 e1 = *(const float4*)&Est[kk][4];      // broadcast
            const float ev[8] = {e0.x, e0.y, e0.z, e0.w,
                                 e1.x, e1.y, e1.z, e1.w};
            #pragma unroll
            for (int h = 0; h < 8; ++h) {
                const float em = bit ? ev[h] : 0.0f;
                den[h] += em;
                num[h] = fmaf(em, x, num[h]);
            }
        }
        #pragma unroll
        for (int h = 0; h < 8; ++h)
            pdn[wave][h][f] = make_float2(den[h], num[h]);
    }
    __syncthreads();

    // ---- P3: combine sections, build xs ----
    {
        const int h = wave, f = lane;
        float den = 0.0f, num = 0.0f;
        #pragma unroll
        for (int ks = 0; ks < 8; ++ks) {
            const float2 v = pdn[ks][h][f];
            den += v.x; num += v.y;
        }
        float outX, outM;
        if (den > 0.0f) {
            outX = num / den;
            outM = 1.0f;                    // sum_k p*mask == den/den
        } else {
            // all-masked column: reference softmax is uniform 1/TK
            const float* Xrow = X + b * TK * F + f;
            float sX = 0.0f;
            for (int kk = 0; kk < TK; ++kk) sX += Xrow[kk * F];
            outX = sX * (1.0f / TK);
            outM = 0.0f;
        }
        xs[h * D + f]      = outX;
        xs[h * D + 64 + f] = outM;
    }
    __syncthreads();

    // ---- P4: out-projection, 32 parts x 16 e4-groups ----
    {
        const int e4 = (tid & 15) * 4;
        const int p  = tid >> 4;            // 0..31
        const int j0 = p * 32;
        float ax = 0, ay = 0, az = 0, aw = 0;
        #pragma unroll 8
        for (int i = 0; i < 32; ++i) {
            const int j = j0 + i;
            const float xj = xs[j];                           // broadcast
            const float4 w = *(const float4*)&Wo[j * ET + e4];// L2-hot
            ax = fmaf(xj, w.x, ax); ay = fmaf(xj, w.y, ay);
            az = fmaf(xj, w.z, az); aw = fmaf(xj, w.w, aw);
        }
        *(float4*)&red[p][e4] = make_float4(ax, ay, az, aw);
    }
    __syncthreads();

    // ---- P5: final reduce + bias + store ----
    if (tid < ET) {
        float acc = bo[tid];
        #pragma unroll
        for (int p = 0; p < 32; ++p) acc += red[p][tid];
        out[(b * TQ + q) * ET + tid] = acc;
    }
}

extern "C" void kernel_launch(void* const* d_in, const int* in_sizes, int n_in,
                              void* d_out, int out_size, void* d_ws, size_t ws_size,
                              hipStream_t stream) {
    const float* X      = (const float*)d_in[0];
    const float* mask_X = (const float*)d_in[1];
    const float* T      = (const float*)d_in[2];
    const float* alpha  = (const float*)d_in[3];
    const float* w_lin  = (const float*)d_in[4];
    const float* b_lin  = (const float*)d_in[5];
    const float* w_per  = (const float*)d_in[6];
    const float* b_per  = (const float*)d_in[7];
    const float* Wq     = (const float*)d_in[8];
    const float* bq     = (const float*)d_in[9];
    const float* Wk     = (const float*)d_in[10];
    const float* bk     = (const float*)d_in[11];
    const float* Wo     = (const float*)d_in[12];
    const float* bo     = (const float*)d_in[13];
    float* out = (float*)d_out;

    float* kws = (float*)d_ws;                    // B*H*TK*DK = 65536 floats
    float* qws = kws + B * H * TK * DK;           // B*TQ*ET   = 24576 floats

    embed_proj_kernel<<<dim3((B * TK + B * TQ) / 4), dim3(256), 0, stream>>>(
        T, alpha, w_lin, b_lin, w_per, b_per, Wq, bq, Wk, bk, kws, qws);

    attn_kernel<<<dim3(B * TQ), dim3(512), 0, stream>>>(
        X, mask_X, kws, qws, Wo, bo, out);
}

// Round 7
// 97.982 us; speedup vs baseline: 1.0297x; 1.0117x over previous
//
#include <hip/hip_runtime.h>
#include <math.h>

#define B   8
#define TQ  48
#define TK  128
#define F   64
#define ET  64
#define H   8
#define DK  8
#define D   128   // 2*F

// ---------------------------------------------------------------------------
// Kernel A: time-embed + linear projection for keys (T, Wk) and queries
// (alpha, Wq). One wave per row; 4 rows per block; 352 blocks.
// Key output layout [B,H,TK,DK] so kernel B reads contiguous DK=8 chunks.
// ---------------------------------------------------------------------------
__global__ __launch_bounds__(256) void embed_proj_kernel(
    const float* __restrict__ T,      // [B,TK]
    const float* __restrict__ alpha,  // [B,TQ]
    const float* __restrict__ w_lin, const float* __restrict__ b_lin,
    const float* __restrict__ w_per, const float* __restrict__ b_per,
    const float* __restrict__ Wq, const float* __restrict__ bq,
    const float* __restrict__ Wk, const float* __restrict__ bk,
    float* __restrict__ kws,          // [B,H,TK,DK]
    float* __restrict__ qws)          // [B,TQ,ET]
{
    __shared__ float es[4][ET];
    const int tid = threadIdx.x;
    const int rl  = tid >> 6;
    const int o   = tid & 63;
    const int row = blockIdx.x * 4 + rl;   // 0..1407

    const bool is_key = row < B * TK;
    const float t = is_key ? T[row] : alpha[row - B * TK];

    float e;
    if (o == 0) e = t * w_lin[0] + b_lin[0];
    else        e = sinf(t * w_per[o - 1] + b_per[o - 1]);
    es[rl][o] = e;
    __syncthreads();

    const float* Wp   = is_key ? Wk : Wq;
    const float* bias = is_key ? bk : bq;
    float acc = bias[o];
    #pragma unroll 8
    for (int i = 0; i < ET; ++i)
        acc = fmaf(es[rl][i], Wp[i * ET + o], acc);

    if (is_key) {
        const int b  = row >> 7;
        const int kk = row & 127;
        const int h  = o >> 3;
        const int dk = o & 7;
        kws[((b * H + h) * TK + kk) * DK + dk] = acc;
    } else {
        const int r = row - B * TK;
        qws[r * ET + o] = acc;
    }
}

// ---------------------------------------------------------------------------
// Kernel B v3: one block per (b,q), 512 threads, 4 barriers.
//  P1 (barrier-free, per-wave): wave w owns head h=w:
//      mask ballots -> Mb; scores via float4 kws reads; full-wave64 shfl max;
//      exp; write Est[k][h] (transposed).
//  P2: thread=(ksec=wave, f): 16 k's, X[k][f] read ONCE from L2 (coalesced),
//      update all 8 heads in registers; inner loop is 2 FMA/head via
//      bitf/xm (no per-head cndmask).
//      (exp(-10000-max)==0.0f exactly in f32 -> masked terms exactly 0,
//       matching the reference's masked_fill path)
//  P3: thread=(h=wave, f=lane): combine 8 sections, outX=num/den,
//      channel f+64: sum_k p*mask = den/den = 1 (0 if all-masked)
//  P4: projection x[1024] @ Wo[1024,64]: 32 parts x 16 e4-groups, float4
//  P5: final 32-way reduce + bias + store
// ---------------------------------------------------------------------------
__global__ __launch_bounds__(512) void attn_kernel(
    const float* __restrict__ X,     // [B,TK,F]
    const float* __restrict__ mask,  // [B,TK,F]
    const float* __restrict__ kws,   // [B,H,TK,DK]
    const float* __restrict__ qws,   // [B,TQ,ET]
    const float* __restrict__ Wo,    // [H*D, ET]
    const float* __restrict__ bo,    // [ET]
    float* __restrict__ out)         // [B,TQ,ET]
{
    __shared__ float Est[TK][H];                 // 4 KB, E transposed
    __shared__ unsigned long long Mb[TK];        // 1 KB
    __shared__ float pden[8][H][F];              // 16 KB den partials
    __shared__ float pnum[8][H][F];              // 16 KB num partials
    __shared__ float xs[H * D];                  // 4 KB
    __shared__ float red[32][ET];                // 8 KB   (~49 KB total)

    const int tid  = threadIdx.x;                // 0..511
    const int wave = tid >> 6, lane = tid & 63;
    const int b = blockIdx.x / TQ;
    const int q = blockIdx.x % TQ;

    // ---- P1: per-wave, no inter-wave dependencies ----
    {
        const float* mrow = mask + b * TK * F;
        #pragma unroll 4
        for (int i = 0; i < 16; ++i) {
            const int kk = wave * 16 + i;
            const unsigned long long bal = __ballot(mrow[kk * F + lane] != 0.0f);
            if (lane == 0) Mb[kk] = bal;
        }

        const float* qrow = qws + (b * TQ + q) * ET + wave * DK;
        float qh[8];
        #pragma unroll
        for (int d = 0; d < 8; ++d) qh[d] = qrow[d];   // wave-uniform

        const float4* k4 = (const float4*)(kws + (b * H + wave) * TK * DK);
        const float4 a0 = k4[lane * 2 + 0];
        const float4 a1 = k4[lane * 2 + 1];
        const float4 c0 = k4[(lane + 64) * 2 + 0];
        const float4 c1 = k4[(lane + 64) * 2 + 1];
        const float inv = 0.35355339059327373f;        // 1/sqrt(8)
        float s0 = (a0.x*qh[0] + a0.y*qh[1] + a0.z*qh[2] + a0.w*qh[3]
                  + a1.x*qh[4] + a1.y*qh[5] + a1.z*qh[6] + a1.w*qh[7]) * inv;
        float s1 = (c0.x*qh[0] + c0.y*qh[1] + c0.z*qh[2] + c0.w*qh[3]
                  + c1.x*qh[4] + c1.y*qh[5] + c1.z*qh[6] + c1.w*qh[7]) * inv;

        float m = fmaxf(s0, s1);
        #pragma unroll
        for (int dlt = 32; dlt >= 1; dlt >>= 1)
            m = fmaxf(m, __shfl_xor(m, dlt));          // all-64-lane max

        Est[lane][wave]      = expf(s0 - m);
        Est[lane + 64][wave] = expf(s1 - m);
    }
    __syncthreads();

    // ---- P2: k-section accumulate; X read once per (k,f) per block ----
    {
        const int f = lane;
        const float* Xrow = X + b * TK * F + f;
        float den[8], num[8];
        #pragma unroll
        for (int h = 0; h < 8; ++h) { den[h] = 0.0f; num[h] = 0.0f; }
        const int k0 = wave * 16;
        #pragma unroll 4
        for (int i = 0; i < 16; ++i) {
            const int kk = k0 + i;
            const float x = Xrow[kk * F];                       // coalesced L2
            const float bitf =
                (float)((unsigned int)(Mb[kk] >> f) & 1u);      // 0.0 or 1.0
            const float xm = x * bitf;
            const float4 e0 = *(const float4*)&Est[kk][0];      // broadcast
            const float4 e1 = *(const float4*)&Est[kk][4];      // broadcast
            const float ev[8] = {e0.x, e0.y, e0.z, e0.w,
                                 e1.x, e1.y, e1.z, e1.w};
            #pragma unroll
            for (int h = 0; h < 8; ++h) {
                den[h] = fmaf(ev[h], bitf, den[h]);
                num[h] = fmaf(ev[h], xm,   num[h]);
            }
        }
        #pragma unroll
        for (int h = 0; h < 8; ++h) {
            pden[wave][h][f] = den[h];
            pnum[wave][h][f] = num[h];
        }
    }
    __syncthreads();

    // ---- P3: combine sections, build xs ----
    {
        const int h = wave, f = lane;
        float den = 0.0f, num = 0.0f;
        #pragma unroll
        for (int ks = 0; ks < 8; ++ks) {
            den += pden[ks][h][f];
            num += pnum[ks][h][f];
        }
        float outX, outM;
        if (den > 0.0f) {
            outX = num / den;
            outM = 1.0f;                    // sum_k p*mask == den/den
        } else {
            // all-masked column: reference softmax is uniform 1/TK
            const float* Xrow = X + b * TK * F + f;
            float sX = 0.0f;
            for (int kk = 0; kk < TK; ++kk) sX += Xrow[kk * F];
            outX = sX * (1.0f / TK);
            outM = 0.0f;
        }
        xs[h * D + f]      = outX;
        xs[h * D + 64 + f] = outM;
    }
    __syncthreads();

    // ---- P4: out-projection, 32 parts x 16 e4-groups ----
    {
        const int e4 = (tid & 15) * 4;
        const int p  = tid >> 4;            // 0..31
        const int j0 = p * 32;
        float ax = 0, ay = 0, az = 0, aw = 0;
        #pragma unroll 8
        for (int i = 0; i < 32; ++i) {
            const int j = j0 + i;
            const float xj = xs[j];                           // broadcast
            const float4 w = *(const float4*)&Wo[j * ET + e4];// L2-hot
            ax = fmaf(xj, w.x, ax); ay = fmaf(xj, w.y, ay);
            az = fmaf(xj, w.z, az); aw = fmaf(xj, w.w, aw);
        }
        *(float4*)&red[p][e4] = make_float4(ax, ay, az, aw);
    }
    __syncthreads();

    // ---- P5: final reduce + bias + store ----
    if (tid < ET) {
        float acc = bo[tid];
        #pragma unroll
        for (int p = 0; p < 32; ++p) acc += red[p][tid];
        out[(b * TQ + q) * ET + tid] = acc;
    }
}

extern "C" void kernel_launch(void* const* d_in, const int* in_sizes, int n_in,
                              void* d_out, int out_size, void* d_ws, size_t ws_size,
                              hipStream_t stream) {
    const float* X      = (const float*)d_in[0];
    const float* mask_X = (const float*)d_in[1];
    const float* T      = (const float*)d_in[2];
    const float* alpha  = (const float*)d_in[3];
    const float* w_lin  = (const float*)d_in[4];
    const float* b_lin  = (const float*)d_in[5];
    const float* w_per  = (const float*)d_in[6];
    const float* b_per  = (const float*)d_in[7];
    const float* Wq     = (const float*)d_in[8];
    const float* bq     = (const float*)d_in[9];
    const float* Wk     = (const float*)d_in[10];
    const float* bk     = (const float*)d_in[11];
    const float* Wo     = (const float*)d_in[12];
    const float* bo     = (const float*)d_in[13];
    float* out = (float*)d_out;

    float* kws = (float*)d_ws;                    // B*H*TK*DK = 65536 floats
    float* qws = kws + B * H * TK * DK;           // B*TQ*ET   = 24576 floats

    embed_proj_kernel<<<dim3((B * TK + B * TQ) / 4), dim3(256), 0, stream>>>(
        T, alpha, w_lin, b_lin, w_per, b_per, Wq, bq, Wk, bk, kws, qws);

    attn_kernel<<<dim3(B * TQ), dim3(512), 0, stream>>>(
        X, mask_X, kws, qws, Wo, bo, out);
}